// Round 6
// baseline (136.649 us; speedup 1.0000x reference)
//
#include <hip/hip_runtime.h>
#include <math.h>

#define DD   41     // depth bins
#define FHh  32
#define HH   16     // h per half-block
#define FWw  88
#define CC   64     // camera channels
#define CG   16     // channels per rowgather block
#define NXx  200
#define NZz  200
#define NCH  (DD + CC)              // 105
#define PLANE ((size_t)FHh * FWw)   // 2816
#define NE   (DD * FWw)             // 3608 entries per (batch, half)
#define ROWCAP 256
// x: (B, 105, 32, 88) fp32 ; out: (B, 64, 200, 200) fp32

// ---------- Kernel A: per-(b,w,h-half) column pool ----------
__global__ __launch_bounds__(256) void lss_colpool(
    const float* __restrict__ x,
    const float* __restrict__ intrins,
    const float* __restrict__ post_rots,
    const float* __restrict__ post_trans,
    float* __restrict__ P0, float* __restrict__ P1,
    int* __restrict__ V0, int* __restrict__ V1,
    int* __restrict__ rowcnt, int* __restrict__ rowlist)
{
    __shared__ float Wt[DD][HH + 1];   // logits -> masked softmax weights (+1 pad)
    __shared__ float F[HH][CC];        // feats [hl][c]
    __shared__ float Mi[18];           // inv(post_rots), inv(intrins)
    __shared__ int   Vtmp[DD];

    int blk  = blockIdx.x;
    int half = blk & 1;
    int w    = (blk >> 1) % FWw;
    int b    = blk / (2 * FWw);
    int t    = threadIdx.x;
    int h0   = half * HH;
    const float* xb = x + (size_t)b * NCH * PLANE + w;

    for (int idx = t; idx < DD * HH; idx += 256) {
        int d = idx >> 4, hl = idx & 15;
        Wt[d][hl] = xb[((size_t)d * FHh + h0 + hl) * FWw];
    }
    for (int idx = t; idx < HH * CC; idx += 256) {
        int c = idx & 63, hl = idx >> 6;
        F[hl][c] = xb[((size_t)(DD + c) * FHh + h0 + hl) * FWw];
    }
    if (t >= 64 && t < 64 + DD) Vtmp[t - 64] = -1;
    if (t == 0) {
        #pragma clang fp contract(off)
        // adjugate inverse; exact for identity rots / triangular K -> entries
        // are single correctly-rounded divisions, matching jnp.linalg.inv.
        for (int m = 0; m < 2; ++m) {
            const float* A = (m == 0 ? post_rots : intrins) + b * 9;
            float* O = Mi + m * 9;
            float a = A[0], bb = A[1], c = A[2];
            float d = A[3], e  = A[4], f = A[5];
            float g = A[6], h  = A[7], i = A[8];
            float det = a * (e * i - f * h) - bb * (d * i - f * g) + c * (d * h - e * g);
            O[0] = (e * i - f * h) / det;
            O[1] = (c * h - bb * i) / det;
            O[2] = (bb * f - c * e) / det;
            O[3] = (f * g - d * i) / det;
            O[4] = (a * i - c * g) / det;
            O[5] = (c * d - a * f) / det;
            O[6] = (d * h - e * g) / det;
            O[7] = (bb * g - a * h) / det;
            O[8] = (a * e - bb * d) / det;
        }
    }
    __syncthreads();

    // ---- parallel softmax + geometry: 16 h-groups x 16 lanes ----
    {
        #pragma clang fp contract(off)
        int hl = t >> 4, l = t & 15;
        // lane l owns depth bins d = l, l+16, (l+32 if l<9)
        float v0 = Wt[l][hl];
        float v1 = Wt[l + 16][hl];
        float v2 = (l < 9) ? Wt[l + 32][hl] : -INFINITY;
        float mx = fmaxf(v0, fmaxf(v1, v2));
        #pragma unroll
        for (int s = 8; s > 0; s >>= 1) mx = fmaxf(mx, __shfl_xor(mx, s, 16));
        float e0 = expf(v0 - mx);
        float e1 = expf(v1 - mx);
        float e2 = (l < 9) ? expf(v2 - mx) : 0.0f;
        float ssum = e0 + e1 + e2;
        #pragma unroll
        for (int s = 8; s > 0; s >>= 1) ssum += __shfl_xor(ssum, s, 16);

        float xs = (float)((double)w * 703.0 / 87.0);          // linspace(0,703,88)
        float ys = (float)((double)(h0 + hl) * 255.0 / 31.0);  // linspace(0,255,32)
        float tx = post_trans[b * 3 + 0];
        float ty = post_trans[b * 3 + 1];
        float tz = post_trans[b * 3 + 2];
        for (int j = 0; j < 3; ++j) {
            int d = l + 16 * j;
            if (d >= DD) break;
            float ee = (j == 0) ? e0 : (j == 1) ? e1 : e2;
            float z  = 4.0f + (float)d;
            float px = xs - tx, py = ys - ty, pz = z - tz;
            float rx = Mi[0] * px + Mi[1] * py + Mi[2] * pz;
            float ry = Mi[3] * px + Mi[4] * py + Mi[5] * pz;
            float rz = Mi[6] * px + Mi[7] * py + Mi[8] * pz;
            float qx = rx * rz, qy = ry * rz, qz = rz;
            float gx = Mi[ 9] * qx + Mi[10] * qy + Mi[11] * qz;
            float gy = Mi[12] * qx + Mi[13] * qy + Mi[14] * qz;
            float gz = Mi[15] * qx + Mi[16] * qy + Mi[17] * qz;
            float cx = (gx + 50.0f) / 0.5f;
            float cy = (gy + 10.0f) / 20.0f;
            float cz = gz / 0.25f;
            int ix = (int)cx;   // trunc == numpy astype(int32)
            int iy = (int)cy;
            int iz = (int)cz;
            bool kept = (ix >= 0) & (ix < NXx) & (iy == 0) & (iz >= 0) & (iz < NZz);
            if (kept) {
                Wt[d][hl] = ee / ssum;
                Vtmp[d] = iz * NXx + ix;   // h-invariant voxel (benign same-value race)
            } else {
                Wt[d][hl] = 0.0f;
            }
        }
    }
    __syncthreads();

    // ---- V + row-list append (one thread per d) ----
    int* Vh = half ? V1 : V0;
    if (t < DD) {
        int v = Vtmp[t];
        Vh[(size_t)b * NE + (size_t)t * FWw + w] = v;
        if (v >= 0) {
            int iz = v / NXx;
            int ix = v - iz * NXx;
            int r = b * NZz + iz;
            int k = atomicAdd(&rowcnt[r], 1);
            int e = t * FWw + w;                   // < 4096
            if (k < ROWCAP) rowlist[r * ROWCAP + k] = (ix << 13) | (half << 12) | e;
        }
    }

    // ---- partial pool: P[d][c] = sum_{h in half} Wt[d][h] * F[h][c] ----
    float* Ph = half ? P1 : P0;
    float* Pb = Ph + ((size_t)b * NE) * CC;
    for (int idx = t; idx < DD * CC; idx += 256) {
        int d = idx >> 6, c = idx & 63;
        float acc = 0.0f;
        for (int hl = 0; hl < HH; ++hl) acc += Wt[d][hl] * F[hl][c];
        Pb[((size_t)d * FWw + w) * CC + c] = acc;   // 256B coalesced
    }
}

// ---------- Kernel B: per-(b, iz, channel-group) row writer ----------
__global__ __launch_bounds__(256) void lss_rowgather(
    const float* __restrict__ P0, const float* __restrict__ P1,
    const int* __restrict__ V0, const int* __restrict__ V1,
    const int* __restrict__ rowcnt, const int* __restrict__ rowlist,
    float* __restrict__ out)
{
    __shared__ float acc[CG * (NXx + 1)];

    int blk = blockIdx.x;          // (b*NZz + iz)*4 + cg
    int cg  = blk & 3;
    int row = blk >> 2;
    int iz  = row % NZz;
    int b   = row / NZz;
    int t   = threadIdx.x;

    int n = rowcnt[row];           // uniform
    float* orow = out + ((size_t)(b * CC + cg * CG)) * (NZz * NXx) + (size_t)iz * NXx;

    if (n == 0) {
        float4 z = make_float4(0.f, 0.f, 0.f, 0.f);
        for (int i = t; i < CG * (NXx / 4); i += 256) {
            int c = i / (NXx / 4), q = i - c * (NXx / 4);
            ((float4*)(orow + (size_t)c * (NZz * NXx)))[q] = z;
        }
        return;
    }

    for (int i = t; i < CG * (NXx + 1); i += 256) acc[i] = 0.0f;
    __syncthreads();

    if (n <= ROWCAP) {
        int j = t & 15;
        const int* rl = rowlist + row * ROWCAP;
        for (int k = t >> 4; k < n; k += 16) {
            int ent  = rl[k];
            int ix   = ent >> 13;
            int half = (ent >> 12) & 1;
            int e    = ent & 0xFFF;
            const float* Pb = (half ? P1 : P0) + ((size_t)b * NE + e) * CC + cg * CG;
            atomicAdd(&acc[j * (NXx + 1) + ix], Pb[j]);
        }
    } else {
        // generic overflow fallback: direct rescan of both halves
        int lo = iz * NXx;
        for (int e = t; e < NE; e += 256) {
            int v = V0[(size_t)b * NE + e];
            if (v >= lo && v < lo + NXx) {
                int ix = v - lo;
                const float* Pe = P0 + ((size_t)b * NE + e) * CC + cg * CG;
                for (int j = 0; j < CG; ++j) atomicAdd(&acc[j * (NXx + 1) + ix], Pe[j]);
            }
            v = V1[(size_t)b * NE + e];
            if (v >= lo && v < lo + NXx) {
                int ix = v - lo;
                const float* Pe = P1 + ((size_t)b * NE + e) * CC + cg * CG;
                for (int j = 0; j < CG; ++j) atomicAdd(&acc[j * (NXx + 1) + ix], Pe[j]);
            }
        }
    }
    __syncthreads();

    for (int i = t; i < CG * (NXx / 4); i += 256) {
        int c = i / (NXx / 4), q = i - c * (NXx / 4);
        int base = c * (NXx + 1) + q * 4;
        float4 v;
        v.x = acc[base + 0];
        v.y = acc[base + 1];
        v.z = acc[base + 2];
        v.w = acc[base + 3];
        ((float4*)(orow + (size_t)c * (NZz * NXx)))[q] = v;
    }
}

extern "C" void kernel_launch(void* const* d_in, const int* in_sizes, int n_in,
                              void* d_out, int out_size, void* d_ws, size_t ws_size,
                              hipStream_t stream)
{
    const float* x          = (const float*)d_in[0];
    const float* intrins    = (const float*)d_in[1];
    const float* post_rots  = (const float*)d_in[2];
    const float* post_trans = (const float*)d_in[3];
    float* out = (float*)d_out;

    int B = in_sizes[0] / (NCH * (int)PLANE);

    // workspace layout (256B-aligned chunks)
    size_t off = 0;
    auto alloc = [&](size_t bytes) {
        void* p = (char*)d_ws + off;
        off = (off + bytes + 255) & ~(size_t)255;
        return p;
    };
    float* P0     = (float*)alloc((size_t)B * NE * CC * sizeof(float));
    float* P1     = (float*)alloc((size_t)B * NE * CC * sizeof(float));
    int*   V0     = (int*)  alloc((size_t)B * NE * sizeof(int));
    int*   V1     = (int*)  alloc((size_t)B * NE * sizeof(int));
    int*   rowcnt = (int*)  alloc((size_t)B * NZz * sizeof(int));
    int*   rowlist= (int*)  alloc((size_t)B * NZz * ROWCAP * sizeof(int));

    (void)hipMemsetAsync(rowcnt, 0, (size_t)B * NZz * sizeof(int), stream);
    lss_colpool<<<B * FWw * 2, 256, 0, stream>>>(x, intrins, post_rots, post_trans,
                                                 P0, P1, V0, V1, rowcnt, rowlist);
    lss_rowgather<<<B * NZz * 4, 256, 0, stream>>>(P0, P1, V0, V1, rowcnt, rowlist, out);
}

// Round 7
// 117.822 us; speedup vs baseline: 1.1598x; 1.1598x over previous
//
#include <hip/hip_runtime.h>
#include <math.h>

#define DD   41     // depth bins
#define FHh  32
#define FWw  88
#define CC   64     // camera channels
#define NXx  200
#define NZz  200
#define NCH  (DD + CC)              // 105
#define PLANE ((size_t)FHh * FWw)   // 2816
#define NE   (DD * FWw)             // 3608
#define DCAP 4                      // d's per output row before fallback
// x: (B, 105, 32, 88) fp32 ; out: (B, 64, 200, 200) fp32

// ---------- Kernel A: per-(b,w) column pool ----------
__global__ __launch_bounds__(256) void lss_colpool(
    const float* __restrict__ x,
    const float* __restrict__ intrins,
    const float* __restrict__ post_rots,
    const float* __restrict__ post_trans,
    float* __restrict__ P, int* __restrict__ V, int* __restrict__ rowcnt)
{
    __shared__ float Wt[DD][FHh];   // depth logits -> masked softmax weights
    __shared__ float F[FHh][CC];    // feats [h][c]
    __shared__ float Mi[18];        // inv(post_rots), inv(intrins)
    __shared__ int   Vtmp[DD];

    int blk = blockIdx.x;
    int w = blk % FWw;
    int b = blk / FWw;
    int t = threadIdx.x;
    const float* xb = x + (size_t)b * NCH * PLANE + w;

    for (int idx = t; idx < DD * FHh; idx += 256) {
        int d = idx >> 5, h = idx & 31;
        Wt[d][h] = xb[((size_t)d * FHh + h) * FWw];
    }
    for (int idx = t; idx < FHh * CC; idx += 256) {
        int c = idx & 63, h = idx >> 6;
        F[h][c] = xb[((size_t)(DD + c) * FHh + h) * FWw];
    }
    if (t >= 64 && t < 64 + DD) Vtmp[t - 64] = -1;
    if (t == 0) {
        #pragma clang fp contract(off)
        // adjugate inverse; exact for identity rots / triangular K -> entries
        // are single correctly-rounded divisions, matching jnp.linalg.inv.
        for (int m = 0; m < 2; ++m) {
            const float* A = (m == 0 ? post_rots : intrins) + b * 9;
            float* O = Mi + m * 9;
            float a = A[0], bb = A[1], c = A[2];
            float d = A[3], e  = A[4], f = A[5];
            float g = A[6], h  = A[7], i = A[8];
            float det = a * (e * i - f * h) - bb * (d * i - f * g) + c * (d * h - e * g);
            O[0] = (e * i - f * h) / det;
            O[1] = (c * h - bb * i) / det;
            O[2] = (bb * f - c * e) / det;
            O[3] = (f * g - d * i) / det;
            O[4] = (a * i - c * g) / det;
            O[5] = (c * d - a * f) / det;
            O[6] = (d * h - e * g) / det;
            O[7] = (bb * g - a * h) / det;
            O[8] = (a * e - bb * d) / det;
        }
    }
    __syncthreads();

    if (t < FHh) {
        #pragma clang fp contract(off)
        int h = t;
        float mx = -INFINITY;
        for (int d = 0; d < DD; ++d) mx = fmaxf(mx, Wt[d][h]);
        float s = 0.0f;
        for (int d = 0; d < DD; ++d) { float e = expf(Wt[d][h] - mx); Wt[d][h] = e; s += e; }

        float xs = (float)((double)w * 703.0 / 87.0);   // linspace(0,703,88)
        float ys = (float)((double)h * 255.0 / 31.0);   // linspace(0,255,32)
        float tx = post_trans[b * 3 + 0];
        float ty = post_trans[b * 3 + 1];
        float tz = post_trans[b * 3 + 2];
        for (int d = 0; d < DD; ++d) {
            float z  = 4.0f + (float)d;
            float px = xs - tx, py = ys - ty, pz = z - tz;
            float rx = Mi[0] * px + Mi[1] * py + Mi[2] * pz;
            float ry = Mi[3] * px + Mi[4] * py + Mi[5] * pz;
            float rz = Mi[6] * px + Mi[7] * py + Mi[8] * pz;
            float qx = rx * rz, qy = ry * rz, qz = rz;
            float gx = Mi[ 9] * qx + Mi[10] * qy + Mi[11] * qz;
            float gy = Mi[12] * qx + Mi[13] * qy + Mi[14] * qz;
            float gz = Mi[15] * qx + Mi[16] * qy + Mi[17] * qz;
            float cx = (gx + 50.0f) / 0.5f;
            float cy = (gy + 10.0f) / 20.0f;
            float cz = gz / 0.25f;
            int ix = (int)cx;   // trunc == numpy astype(int32)
            int iy = (int)cy;
            int iz = (int)cz;
            bool kept = (ix >= 0) & (ix < NXx) & (iy == 0) & (iz >= 0) & (iz < NZz);
            if (kept) {
                Wt[d][h] /= s;
                Vtmp[d] = iz * NXx + ix;   // h-invariant voxel (benign same-value race)
            } else {
                Wt[d][h] = 0.0f;
            }
        }
    }
    __syncthreads();

    // P[b][d][w][c] = sum_h Wt[d][h] * F[h][c]   (coalesced 256B in c)
    float* Pb = P + ((size_t)b * NE) * CC;
    for (int idx = t; idx < DD * CC; idx += 256) {
        int d = idx >> 6, c = idx & 63;
        float acc = 0.0f;
        for (int h = 0; h < FHh; ++h) acc += Wt[d][h] * F[h][c];
        Pb[((size_t)d * FWw + w) * CC + c] = acc;
    }
    if (t < DD) V[(size_t)b * NE + (size_t)t * FWw + w] = Vtmp[t];
    if (w == 0) for (int i = t; i < NZz; i += 256) rowcnt[b * NZz + i] = 0;
}

// ---------- Kernel B: per-(b,d) dense S-row build ----------
__global__ __launch_bounds__(256) void lss_rowbuild(
    const float* __restrict__ P, const int* __restrict__ V,
    float* __restrict__ S, int* __restrict__ izd,
    int* __restrict__ rowcnt, int* __restrict__ dlist)
{
    __shared__ float accf[CC * (NXx + 1)];   // 64 x 201 -> 2-way alias only (free)
    __shared__ int   ixw[FWw];
    __shared__ int   s_iz;

    int bd = blockIdx.x;
    int d  = bd % DD;
    int b  = bd / DD;
    int t  = threadIdx.x;

    if (t == 0) s_iz = -1;
    __syncthreads();
    if (t < FWw) {
        int v = V[((size_t)b * DD + d) * FWw + t];
        int iz = v / NXx;
        ixw[t] = (v >= 0) ? (v - iz * NXx) : -1;
        if (v >= 0) s_iz = iz;      // benign same-value race (iz is w-invariant here)
    }
    __syncthreads();
    int iz = s_iz;
    if (t == 0) izd[b * DD + d] = iz;
    if (iz < 0) return;             // no kept points for this (b,d)
    if (t == 0) {
        int r = b * NZz + iz;
        int k = atomicAdd(&rowcnt[r], 1);
        if (k < DCAP) dlist[r * DCAP + k] = d;
    }

    for (int i = t; i < CC * (NXx + 1); i += 256) accf[i] = 0.0f;
    __syncthreads();

    // coalesced read of the whole P slab [w][c] for this (b,d)
    const float* Pb = P + ((size_t)b * DD + d) * FWw * CC;
    for (int idx = t; idx < FWw * CC; idx += 256) {
        int w = idx >> 6, c = idx & 63;
        int ix = ixw[w];
        if (ix >= 0) atomicAdd(&accf[c * (NXx + 1) + ix], Pb[idx]);
    }
    __syncthreads();

    // dense S row [c][200], float4 linear
    float* Srow = S + ((size_t)b * DD + d) * CC * NXx;
    for (int i = t; i < CC * (NXx / 4); i += 256) {
        int c = i / (NXx / 4), q = i - c * (NXx / 4);
        int base = c * (NXx + 1) + q * 4;
        float4 vv;
        vv.x = accf[base + 0];
        vv.y = accf[base + 1];
        vv.z = accf[base + 2];
        vv.w = accf[base + 3];
        ((float4*)Srow)[i] = vv;
    }
}

// ---------- Kernel C: pure streaming writer ----------
// block = (b, c, iz-quarter): writes a contiguous 40KB span of out.
__global__ __launch_bounds__(256) void lss_writeout(
    const float* __restrict__ S, const int* __restrict__ izd,
    const int* __restrict__ rowcnt, const int* __restrict__ dlist,
    float* __restrict__ out)
{
    __shared__ int s_n[50];
    __shared__ int s_d[50 * DCAP];

    int blk = blockIdx.x;
    int qz = blk & 3;
    int bc = blk >> 2;
    int c  = bc % CC;
    int b  = bc / CC;
    int iz0 = qz * 50;
    int t = threadIdx.x;

    for (int i = t; i < 50; i += 256) s_n[i] = rowcnt[b * NZz + iz0 + i];
    for (int i = t; i < 50 * DCAP; i += 256) s_d[i] = dlist[(size_t)(b * NZz + iz0) * DCAP + i];
    __syncthreads();

    float* obase = out + (((size_t)b * CC + c) * NZz + iz0) * NXx;  // 40KB contiguous
    const float* Sb = S + (size_t)b * DD * CC * NXx;

    for (int i = t; i < 50 * (NXx / 4); i += 256) {     // 2500 float4
        int izl = i / (NXx / 4), q = i - izl * (NXx / 4);
        int n = s_n[izl];
        float4 vv = make_float4(0.f, 0.f, 0.f, 0.f);
        if (n > 0) {
            if (n <= DCAP) {
                for (int k = 0; k < n; ++k) {
                    int d = s_d[izl * DCAP + k];
                    float4 sv = ((const float4*)(Sb + ((size_t)d * CC + c) * NXx))[q];
                    vv.x += sv.x; vv.y += sv.y; vv.z += sv.z; vv.w += sv.w;
                }
            } else {
                // generic fallback: scan all d whose row == this iz
                int iz = iz0 + izl;
                for (int d = 0; d < DD; ++d) {
                    if (izd[b * DD + d] == iz) {
                        float4 sv = ((const float4*)(Sb + ((size_t)d * CC + c) * NXx))[q];
                        vv.x += sv.x; vv.y += sv.y; vv.z += sv.z; vv.w += sv.w;
                    }
                }
            }
        }
        ((float4*)obase)[i] = vv;
    }
}

extern "C" void kernel_launch(void* const* d_in, const int* in_sizes, int n_in,
                              void* d_out, int out_size, void* d_ws, size_t ws_size,
                              hipStream_t stream)
{
    const float* x          = (const float*)d_in[0];
    const float* intrins    = (const float*)d_in[1];
    const float* post_rots  = (const float*)d_in[2];
    const float* post_trans = (const float*)d_in[3];
    float* out = (float*)d_out;

    int B = in_sizes[0] / (NCH * (int)PLANE);

    size_t off = 0;
    auto alloc = [&](size_t bytes) {
        void* p = (char*)d_ws + off;
        off = (off + bytes + 255) & ~(size_t)255;
        return p;
    };
    float* P      = (float*)alloc((size_t)B * NE * CC * sizeof(float));      // 3.7 MB
    int*   V      = (int*)  alloc((size_t)B * NE * sizeof(int));
    float* S      = (float*)alloc((size_t)B * DD * CC * NXx * sizeof(float));// 8.4 MB
    int*   izd    = (int*)  alloc((size_t)B * DD * sizeof(int));
    int*   rowcnt = (int*)  alloc((size_t)B * NZz * sizeof(int));
    int*   dlist  = (int*)  alloc((size_t)B * NZz * DCAP * sizeof(int));

    lss_colpool<<<B * FWw, 256, 0, stream>>>(x, intrins, post_rots, post_trans, P, V, rowcnt);
    lss_rowbuild<<<B * DD, 256, 0, stream>>>(P, V, S, izd, rowcnt, dlist);
    lss_writeout<<<B * CC * 4, 256, 0, stream>>>(S, izd, rowcnt, dlist, out);
}

// Round 8
// 105.867 us; speedup vs baseline: 1.2908x; 1.1129x over previous
//
#include <hip/hip_runtime.h>
#include <math.h>

#define DD   41     // depth bins
#define FHh  32
#define FWw  88
#define CC   64     // camera channels
#define CG8  8      // channels per rowbuild block
#define NXx  200
#define NZz  200
#define NCH  (DD + CC)              // 105
#define PLANE ((size_t)FHh * FWw)   // 2816
#define NE   (DD * FWw)             // 3608
#define DCAP 4
#define OVCAP 4096
// x: (B, 105, 32, 88) fp32 ; out: (B, 64, 200, 200) fp32

// ---------- Kernel A: per-(b,w) column pool ----------
__global__ __launch_bounds__(256) void lss_colpool(
    const float* __restrict__ x,
    const float* __restrict__ intrins,
    const float* __restrict__ post_rots,
    const float* __restrict__ post_trans,
    float* __restrict__ P, int* __restrict__ V,
    int* __restrict__ rowcnt, int* __restrict__ ovcnt)
{
    __shared__ float Wt[DD][FHh + 1];   // logits -> masked softmax weights (pad 33)
    __shared__ float F[FHh][CC];        // feats [h][c]
    __shared__ float Mi[18];            // inv(post_rots), inv(intrins)
    __shared__ float pm[8][FHh + 1];    // per-lane-group partial max / sum
    __shared__ int   Vtmp[DD];

    int blk = blockIdx.x;
    int w = blk % FWw;
    int b = blk / FWw;
    int t = threadIdx.x;
    const float* xb = x + (size_t)b * NCH * PLANE + w;

    for (int idx = t; idx < DD * FHh; idx += 256) {
        int d = idx >> 5, h = idx & 31;
        Wt[d][h] = xb[((size_t)d * FHh + h) * FWw];
    }
    for (int idx = t; idx < FHh * CC; idx += 256) {
        int c = idx & 63, h = idx >> 6;
        F[h][c] = xb[((size_t)(DD + c) * FHh + h) * FWw];
    }
    if (t >= 64 && t < 64 + DD) Vtmp[t - 64] = -1;
    if (t == 0) {
        #pragma clang fp contract(off)
        // adjugate inverse; exact for identity rots / triangular K -> entries
        // are single correctly-rounded divisions, matching jnp.linalg.inv.
        for (int m = 0; m < 2; ++m) {
            const float* A = (m == 0 ? post_rots : intrins) + b * 9;
            float* O = Mi + m * 9;
            float a = A[0], bb = A[1], c = A[2];
            float d = A[3], e  = A[4], f = A[5];
            float g = A[6], h  = A[7], i = A[8];
            float det = a * (e * i - f * h) - bb * (d * i - f * g) + c * (d * h - e * g);
            O[0] = (e * i - f * h) / det;
            O[1] = (c * h - bb * i) / det;
            O[2] = (bb * f - c * e) / det;
            O[3] = (f * g - d * i) / det;
            O[4] = (a * i - c * g) / det;
            O[5] = (c * d - a * f) / det;
            O[6] = (d * h - e * g) / det;
            O[7] = (bb * g - a * h) / det;
            O[8] = (a * e - bb * d) / det;
        }
    }
    __syncthreads();

    // ---- parallel softmax: thread (h = t&31, l = t>>5) owns d = l+8k ----
    int h = t & 31, l = t >> 5;
    float e_[6];
    {
        float pmax = -INFINITY;
        for (int d = l; d < DD; d += 8) pmax = fmaxf(pmax, Wt[d][h]);
        pm[l][h] = pmax;
    }
    __syncthreads();
    float mx = -INFINITY;
    for (int j = 0; j < 8; ++j) mx = fmaxf(mx, pm[j][h]);
    __syncthreads();
    {
        #pragma clang fp contract(off)
        float psum = 0.0f;
        int k = 0;
        for (int d = l; d < DD; d += 8, ++k) {
            float e = expf(Wt[d][h] - mx);
            e_[k] = e; psum += e;
        }
        pm[l][h] = psum;
    }
    __syncthreads();
    float s = 0.0f;
    for (int j = 0; j < 8; ++j) s += pm[j][h];

    // ---- geometry per (d,h), honest mask ----
    {
        #pragma clang fp contract(off)
        float xs = (float)((double)w * 703.0 / 87.0);   // linspace(0,703,88)
        float ys = (float)((double)h * 255.0 / 31.0);   // linspace(0,255,32)
        float tx = post_trans[b * 3 + 0];
        float ty = post_trans[b * 3 + 1];
        float tz = post_trans[b * 3 + 2];
        int k = 0;
        for (int d = l; d < DD; d += 8, ++k) {
            float z  = 4.0f + (float)d;
            float px = xs - tx, py = ys - ty, pz = z - tz;
            float rx = Mi[0] * px + Mi[1] * py + Mi[2] * pz;
            float ry = Mi[3] * px + Mi[4] * py + Mi[5] * pz;
            float rz = Mi[6] * px + Mi[7] * py + Mi[8] * pz;
            float qx = rx * rz, qy = ry * rz, qz = rz;
            float gx = Mi[ 9] * qx + Mi[10] * qy + Mi[11] * qz;
            float gy = Mi[12] * qx + Mi[13] * qy + Mi[14] * qz;
            float gz = Mi[15] * qx + Mi[16] * qy + Mi[17] * qz;
            float cx = (gx + 50.0f) / 0.5f;
            float cy = (gy + 10.0f) / 20.0f;
            float cz = gz / 0.25f;
            int ix = (int)cx;   // trunc == numpy astype(int32)
            int iy = (int)cy;
            int iz = (int)cz;
            bool kept = (ix >= 0) & (ix < NXx) & (iy == 0) & (iz >= 0) & (iz < NZz);
            if (kept) {
                Wt[d][h] = e_[k] / s;
                Vtmp[d] = iz * NXx + ix;   // benign same-value race in practice;
                                           // mismatches handled via overflow path
            } else {
                Wt[d][h] = 0.0f;
            }
        }
    }
    __syncthreads();

    // ---- pool: P[b][d][w][c] = sum_h Wt[d][h]*F[h][c] ----
    float* Pb = P + ((size_t)b * NE) * CC;
    for (int idx = t; idx < DD * CC; idx += 256) {
        int d = idx >> 6, c = idx & 63;
        float acc = 0.0f;
        for (int hh = 0; hh < FHh; ++hh) acc += Wt[d][hh] * F[hh][c];
        Pb[((size_t)d * FWw + w) * CC + c] = acc;   // 256B coalesced
    }
    if (t < DD) V[(size_t)b * NE + (size_t)t * FWw + w] = Vtmp[t];
    if (w == 0) for (int i = t; i < NZz; i += 256) rowcnt[b * NZz + i] = 0;
    if (blk == 0 && t == 0) *ovcnt = 0;
}

// ---------- Kernel B: per-(b,d,8ch) dense S-row build ----------
__global__ __launch_bounds__(256) void lss_rowbuild(
    const float* __restrict__ P, const int* __restrict__ V,
    float* __restrict__ S, int* __restrict__ izd,
    int* __restrict__ rowcnt, int* __restrict__ dlist,
    int* __restrict__ ovcnt, int* __restrict__ ovlist)
{
    __shared__ float acc[CG8 * (NXx + 1)];
    __shared__ int ixw[FWw];
    __shared__ int izw[FWw];
    __shared__ int key;

    int blk = blockIdx.x;
    int cg = blk & 7;
    int bd = blk >> 3;
    int d = bd % DD;
    int b = bd / DD;
    int t = threadIdx.x;

    if (t == 0) key = 0x7fffffff;
    for (int i = t; i < CG8 * (NXx + 1); i += 256) acc[i] = 0.0f;
    __syncthreads();
    if (t < FWw) {
        int v = V[(size_t)bd * FWw + t];
        if (v >= 0) {
            int iz = v / NXx;
            izw[t] = iz; ixw[t] = v - iz * NXx;
            atomicMin(&key, (t << 16) | iz);
        } else { izw[t] = -1; ixw[t] = -1; }
    }
    __syncthreads();
    int kk = key;
    int s_iz = (kk == 0x7fffffff) ? -1 : (kk & 0xffff);  // iz of min-w kept entry
    if (cg == 0 && t == 0) {
        izd[bd] = s_iz;
        if (s_iz >= 0) {
            int r = b * NZz + s_iz;
            int k = atomicAdd(&rowcnt[r], 1);
            if (k < DCAP) dlist[r * DCAP + k] = d;
        }
    }
    if (s_iz < 0) return;

    // generic path: kept entries whose iz != s_iz go to the overflow list
    if (cg == 0 && t < FWw && izw[t] >= 0 && izw[t] != s_iz) {
        int k = atomicAdd(ovcnt, 1);
        if (k < OVCAP)
            ovlist[k] = (b << 29) | (d << 23) | (t << 16) | (ixw[t] << 8) | izw[t];
    }

    const float* Pb = P + (size_t)bd * FWw * CC + cg * CG8;
    for (int idx = t; idx < FWw * CG8; idx += 256) {
        int w = idx >> 3, cl = idx & 7;
        if (izw[w] == s_iz)
            atomicAdd(&acc[cl * (NXx + 1) + ixw[w]], Pb[(size_t)w * CC + cl]);
    }
    __syncthreads();

    float* Srow = S + ((size_t)bd * CC + cg * CG8) * NXx;
    for (int i = t; i < CG8 * (NXx / 4); i += 256) {
        int c = i / (NXx / 4), q = i - c * (NXx / 4);
        int base = c * (NXx + 1) + q * 4;
        float4 vv;
        vv.x = acc[base + 0];
        vv.y = acc[base + 1];
        vv.z = acc[base + 2];
        vv.w = acc[base + 3];
        ((float4*)Srow)[i] = vv;
    }
}

// ---------- Kernel C: pure streaming writer ----------
__global__ __launch_bounds__(256) void lss_writeout(
    const float* __restrict__ S, const int* __restrict__ izd,
    const int* __restrict__ rowcnt, const int* __restrict__ dlist,
    const float* __restrict__ P,
    const int* __restrict__ ovcnt, const int* __restrict__ ovlist,
    float* __restrict__ out)
{
    __shared__ int s_n[50];
    __shared__ int s_d[50 * DCAP];

    int blk = blockIdx.x;
    int qz = blk & 3;
    int bc = blk >> 2;
    int c  = bc % CC;
    int b  = bc / CC;
    int iz0 = qz * 50;
    int t = threadIdx.x;

    for (int i = t; i < 50; i += 256) s_n[i] = rowcnt[b * NZz + iz0 + i];
    for (int i = t; i < 50 * DCAP; i += 256) s_d[i] = dlist[(size_t)(b * NZz + iz0) * DCAP + i];
    __syncthreads();

    float* obase = out + (((size_t)b * CC + c) * NZz + iz0) * NXx;  // 40KB contiguous
    const float* Sb = S + (size_t)b * DD * CC * NXx;

    for (int i = t; i < 50 * (NXx / 4); i += 256) {
        int izl = i / (NXx / 4), q = i - izl * (NXx / 4);
        int n = s_n[izl];
        float4 vv = make_float4(0.f, 0.f, 0.f, 0.f);
        if (n > 0) {
            if (n <= DCAP) {
                for (int k = 0; k < n; ++k) {
                    int d = s_d[izl * DCAP + k];
                    float4 sv = ((const float4*)(Sb + ((size_t)d * CC + c) * NXx))[q];
                    vv.x += sv.x; vv.y += sv.y; vv.z += sv.z; vv.w += sv.w;
                }
            } else {
                int iz = iz0 + izl;
                for (int d = 0; d < DD; ++d) {
                    if (izd[b * DD + d] == iz) {
                        float4 sv = ((const float4*)(Sb + ((size_t)d * CC + c) * NXx))[q];
                        vv.x += sv.x; vv.y += sv.y; vv.z += sv.z; vv.w += sv.w;
                    }
                }
            }
        }
        ((float4*)obase)[i] = vv;
    }

    // never-taken generic overflow fixup (entries with iz != owner's s_iz)
    int nov = *ovcnt;
    if (nov > 0) {
        __syncthreads();
        if (t == 0) {
            if (nov > OVCAP) nov = OVCAP;
            for (int k = 0; k < nov; ++k) {
                int ent = ovlist[k];
                int eb  = (ent >> 29) & 7;
                int ed  = (ent >> 23) & 63;
                int ew  = (ent >> 16) & 127;
                int eix = (ent >> 8) & 255;
                int eiz = ent & 255;
                if (eb == b && eiz >= iz0 && eiz < iz0 + 50) {
                    size_t o = (((size_t)b * CC + c) * NZz + eiz) * NXx + eix;
                    out[o] += P[(((size_t)eb * DD + ed) * FWw + ew) * CC + c];
                }
            }
        }
    }
}

extern "C" void kernel_launch(void* const* d_in, const int* in_sizes, int n_in,
                              void* d_out, int out_size, void* d_ws, size_t ws_size,
                              hipStream_t stream)
{
    const float* x          = (const float*)d_in[0];
    const float* intrins    = (const float*)d_in[1];
    const float* post_rots  = (const float*)d_in[2];
    const float* post_trans = (const float*)d_in[3];
    float* out = (float*)d_out;

    int B = in_sizes[0] / (NCH * (int)PLANE);

    size_t off = 0;
    auto alloc = [&](size_t bytes) {
        void* p = (char*)d_ws + off;
        off = (off + bytes + 255) & ~(size_t)255;
        return p;
    };
    float* P      = (float*)alloc((size_t)B * NE * CC * sizeof(float));       // 3.7 MB
    int*   V      = (int*)  alloc((size_t)B * NE * sizeof(int));
    float* S      = (float*)alloc((size_t)B * DD * CC * NXx * sizeof(float)); // 8.4 MB
    int*   izd    = (int*)  alloc((size_t)B * DD * sizeof(int));
    int*   rowcnt = (int*)  alloc((size_t)B * NZz * sizeof(int));
    int*   dlist  = (int*)  alloc((size_t)B * NZz * DCAP * sizeof(int));
    int*   ovcnt  = (int*)  alloc(256);
    int*   ovlist = (int*)  alloc((size_t)OVCAP * sizeof(int));

    lss_colpool<<<B * FWw, 256, 0, stream>>>(x, intrins, post_rots, post_trans,
                                             P, V, rowcnt, ovcnt);
    lss_rowbuild<<<B * DD * 8, 256, 0, stream>>>(P, V, S, izd, rowcnt, dlist,
                                                 ovcnt, ovlist);
    lss_writeout<<<B * CC * 4, 256, 0, stream>>>(S, izd, rowcnt, dlist, P,
                                                 ovcnt, ovlist, out);
}

// Round 9
// 104.418 us; speedup vs baseline: 1.3087x; 1.0139x over previous
//
#include <hip/hip_runtime.h>
#include <math.h>

#define DD   41     // depth bins
#define FHh  32
#define FWw  88
#define CC   64     // camera channels
#define CH   32     // channels per colpool half
#define CG8  8      // channels per rowbuild block
#define NXx  200
#define NZz  200
#define NCH  (DD + CC)              // 105
#define PLANE ((size_t)FHh * FWw)   // 2816
#define NE   (DD * FWw)             // 3608
#define DCAP 4
#define OVCAP 4096
// x: (B, 105, 32, 88) fp32 ; out: (B, 64, 200, 200) fp32

// ---------- Kernel A: per-(b,w,c-half) column pool ----------
__global__ __launch_bounds__(256) void lss_colpool(
    const float* __restrict__ x,
    const float* __restrict__ intrins,
    const float* __restrict__ post_rots,
    const float* __restrict__ post_trans,
    float* __restrict__ P, int* __restrict__ V,
    int* __restrict__ rowcnt, int* __restrict__ ovcnt)
{
    __shared__ float Wt[DD][FHh + 1];   // logits -> masked softmax weights
    __shared__ float F4s[FHh][36];      // half-F [h][c], row 36 floats (16B-aligned)
    __shared__ float Mi[18];            // inv(post_rots), inv(intrins)
    __shared__ float pm[8][FHh + 1];    // partial max / sum
    __shared__ int   Vtmp[DD];

    int blk   = blockIdx.x;
    int chalf = blk & 1;
    int w     = (blk >> 1) % FWw;
    int b     = blk / (2 * FWw);
    int t     = threadIdx.x;
    const float* xb = x + (size_t)b * NCH * PLANE + w;

    // stage depth logits (full 41x32)
    for (int idx = t; idx < DD * FHh; idx += 256) {
        int d = idx >> 5, h = idx & 31;
        Wt[d][h] = xb[((size_t)d * FHh + h) * FWw];
    }
    // stage this half's feats [h][c]
    for (int idx = t; idx < FHh * CH; idx += 256) {
        int c = idx & 31, h = idx >> 5;
        F4s[h][c] = xb[((size_t)(DD + chalf * CH + c) * FHh + h) * FWw];
    }
    if (t >= 64 && t < 64 + DD) Vtmp[t - 64] = -1;
    if (t == 0) {
        #pragma clang fp contract(off)
        // adjugate inverse; exact for identity rots / triangular K -> entries
        // are single correctly-rounded divisions, matching jnp.linalg.inv.
        for (int m = 0; m < 2; ++m) {
            const float* A = (m == 0 ? post_rots : intrins) + b * 9;
            float* O = Mi + m * 9;
            float a = A[0], bb = A[1], c = A[2];
            float d = A[3], e  = A[4], f = A[5];
            float g = A[6], h  = A[7], i = A[8];
            float det = a * (e * i - f * h) - bb * (d * i - f * g) + c * (d * h - e * g);
            O[0] = (e * i - f * h) / det;
            O[1] = (c * h - bb * i) / det;
            O[2] = (bb * f - c * e) / det;
            O[3] = (f * g - d * i) / det;
            O[4] = (a * i - c * g) / det;
            O[5] = (c * d - a * f) / det;
            O[6] = (d * h - e * g) / det;
            O[7] = (bb * g - a * h) / det;
            O[8] = (a * e - bb * d) / det;
        }
    }
    __syncthreads();

    // ---- parallel softmax: thread (h = t&31, l = t>>5) owns d = l+8k ----
    int h = t & 31, l = t >> 5;
    float e_[6];
    {
        float pmax = -INFINITY;
        for (int d = l; d < DD; d += 8) pmax = fmaxf(pmax, Wt[d][h]);
        pm[l][h] = pmax;
    }
    __syncthreads();
    float mx = -INFINITY;
    for (int j = 0; j < 8; ++j) mx = fmaxf(mx, pm[j][h]);
    __syncthreads();
    {
        #pragma clang fp contract(off)
        float psum = 0.0f;
        int k = 0;
        for (int d = l; d < DD; d += 8, ++k) {
            float e = expf(Wt[d][h] - mx);
            e_[k] = e; psum += e;
        }
        pm[l][h] = psum;
    }
    __syncthreads();
    float s = 0.0f;
    for (int j = 0; j < 8; ++j) s += pm[j][h];

    // ---- geometry per (d,h), honest mask ----
    {
        #pragma clang fp contract(off)
        float xs = (float)((double)w * 703.0 / 87.0);   // linspace(0,703,88)
        float ys = (float)((double)h * 255.0 / 31.0);   // linspace(0,255,32)
        float tx = post_trans[b * 3 + 0];
        float ty = post_trans[b * 3 + 1];
        float tz = post_trans[b * 3 + 2];
        int k = 0;
        for (int d = l; d < DD; d += 8, ++k) {
            float z  = 4.0f + (float)d;
            float px = xs - tx, py = ys - ty, pz = z - tz;
            float rx = Mi[0] * px + Mi[1] * py + Mi[2] * pz;
            float ry = Mi[3] * px + Mi[4] * py + Mi[5] * pz;
            float rz = Mi[6] * px + Mi[7] * py + Mi[8] * pz;
            float qx = rx * rz, qy = ry * rz, qz = rz;
            float gx = Mi[ 9] * qx + Mi[10] * qy + Mi[11] * qz;
            float gy = Mi[12] * qx + Mi[13] * qy + Mi[14] * qz;
            float gz = Mi[15] * qx + Mi[16] * qy + Mi[17] * qz;
            float cx = (gx + 50.0f) / 0.5f;
            float cy = (gy + 10.0f) / 20.0f;
            float cz = gz / 0.25f;
            int ix = (int)cx;   // trunc == numpy astype(int32)
            int iy = (int)cy;
            int iz = (int)cz;
            bool kept = (ix >= 0) & (ix < NXx) & (iy == 0) & (iz >= 0) & (iz < NZz);
            if (kept) {
                Wt[d][h] = e_[k] / s;
                Vtmp[d] = iz * NXx + ix;   // benign same-value race in practice;
                                           // w-mismatches handled via overflow path
            } else {
                Wt[d][h] = 0.0f;
            }
        }
    }
    __syncthreads();

    // ---- pool: P[b][d][w][chalf*32 + c4*4 ..] = sum_h Wt[d][h]*F[h][c] ----
    float* Pb = P + ((size_t)b * NE) * CC + chalf * CH;
    {
        int c4 = t & 7;
        for (int d = t >> 3; d < DD; d += 32) {
            float4 acc = make_float4(0.f, 0.f, 0.f, 0.f);
            for (int hh = 0; hh < FHh; ++hh) {
                float wtv = Wt[d][hh];
                float4 fv = *(const float4*)&F4s[hh][c4 * 4];
                acc.x += wtv * fv.x; acc.y += wtv * fv.y;
                acc.z += wtv * fv.z; acc.w += wtv * fv.w;
            }
            *(float4*)&Pb[((size_t)d * FWw + w) * CC + c4 * 4] = acc;
        }
    }
    if (chalf == 0) {
        if (t < DD) V[(size_t)b * NE + (size_t)t * FWw + w] = Vtmp[t];
        if (w == 0) for (int i = t; i < NZz; i += 256) rowcnt[b * NZz + i] = 0;
    }
    if (blk == 0 && t == 0) *ovcnt = 0;
}

// ---------- Kernel B: per-(b,d,8ch) dense S-row build ----------
__global__ __launch_bounds__(256) void lss_rowbuild(
    const float* __restrict__ P, const int* __restrict__ V,
    float* __restrict__ S, int* __restrict__ izd,
    int* __restrict__ rowcnt, int* __restrict__ dlist,
    int* __restrict__ ovcnt, int* __restrict__ ovlist)
{
    __shared__ float acc[CG8 * (NXx + 1)];
    __shared__ int ixw[FWw];
    __shared__ int izw[FWw];
    __shared__ int key;

    int blk = blockIdx.x;
    int cg = blk & 7;
    int bd = blk >> 3;
    int d = bd % DD;
    int b = bd / DD;
    int t = threadIdx.x;

    if (t == 0) key = 0x7fffffff;
    for (int i = t; i < CG8 * (NXx + 1); i += 256) acc[i] = 0.0f;
    __syncthreads();
    if (t < FWw) {
        int v = V[(size_t)bd * FWw + t];
        if (v >= 0) {
            int iz = v / NXx;
            izw[t] = iz; ixw[t] = v - iz * NXx;
            atomicMin(&key, (t << 16) | iz);
        } else { izw[t] = -1; ixw[t] = -1; }
    }
    __syncthreads();
    int kk = key;
    int s_iz = (kk == 0x7fffffff) ? -1 : (kk & 0xffff);  // iz of min-w kept entry
    if (cg == 0 && t == 0) {
        izd[bd] = s_iz;
        if (s_iz >= 0) {
            int r = b * NZz + s_iz;
            int k = atomicAdd(&rowcnt[r], 1);
            if (k < DCAP) dlist[r * DCAP + k] = d;
        }
    }
    if (s_iz < 0) return;

    // generic path: kept entries whose iz != s_iz go to the overflow list
    if (cg == 0 && t < FWw && izw[t] >= 0 && izw[t] != s_iz) {
        int k = atomicAdd(ovcnt, 1);
        if (k < OVCAP)
            ovlist[k] = (b << 29) | (d << 23) | (t << 16) | (ixw[t] << 8) | izw[t];
    }

    const float* Pb = P + (size_t)bd * FWw * CC + cg * CG8;
    for (int idx = t; idx < FWw * 2; idx += 256) {
        int w = idx >> 1, q = idx & 1;
        if (izw[w] == s_iz) {
            float4 v = *(const float4*)&Pb[(size_t)w * CC + q * 4];
            int ix = ixw[w];
            int cb = q * 4;
            atomicAdd(&acc[(cb + 0) * (NXx + 1) + ix], v.x);
            atomicAdd(&acc[(cb + 1) * (NXx + 1) + ix], v.y);
            atomicAdd(&acc[(cb + 2) * (NXx + 1) + ix], v.z);
            atomicAdd(&acc[(cb + 3) * (NXx + 1) + ix], v.w);
        }
    }
    __syncthreads();

    float* Srow = S + ((size_t)bd * CC + cg * CG8) * NXx;
    for (int i = t; i < CG8 * (NXx / 4); i += 256) {
        int c = i / (NXx / 4), q = i - c * (NXx / 4);
        int base = c * (NXx + 1) + q * 4;
        float4 vv;
        vv.x = acc[base + 0];
        vv.y = acc[base + 1];
        vv.z = acc[base + 2];
        vv.w = acc[base + 3];
        ((float4*)Srow)[i] = vv;
    }
}

// ---------- Kernel C: pure streaming writer ----------
__global__ __launch_bounds__(256) void lss_writeout(
    const float* __restrict__ S, const int* __restrict__ izd,
    const int* __restrict__ rowcnt, const int* __restrict__ dlist,
    const float* __restrict__ P,
    const int* __restrict__ ovcnt, const int* __restrict__ ovlist,
    float* __restrict__ out)
{
    __shared__ int s_n[50];
    __shared__ int s_d[50 * DCAP];

    int blk = blockIdx.x;
    int qz = blk & 3;
    int bc = blk >> 2;
    int c  = bc % CC;
    int b  = bc / CC;
    int iz0 = qz * 50;
    int t = threadIdx.x;

    for (int i = t; i < 50; i += 256) s_n[i] = rowcnt[b * NZz + iz0 + i];
    for (int i = t; i < 50 * DCAP; i += 256) s_d[i] = dlist[(size_t)(b * NZz + iz0) * DCAP + i];
    __syncthreads();

    float* obase = out + (((size_t)b * CC + c) * NZz + iz0) * NXx;  // 40KB contiguous
    const float* Sb = S + (size_t)b * DD * CC * NXx;

    for (int i = t; i < 50 * (NXx / 4); i += 256) {
        int izl = i / (NXx / 4), q = i - izl * (NXx / 4);
        int n = s_n[izl];
        float4 vv = make_float4(0.f, 0.f, 0.f, 0.f);
        if (n > 0) {
            if (n <= DCAP) {
                for (int k = 0; k < n; ++k) {
                    int d = s_d[izl * DCAP + k];
                    float4 sv = ((const float4*)(Sb + ((size_t)d * CC + c) * NXx))[q];
                    vv.x += sv.x; vv.y += sv.y; vv.z += sv.z; vv.w += sv.w;
                }
            } else {
                int iz = iz0 + izl;
                for (int d = 0; d < DD; ++d) {
                    if (izd[b * DD + d] == iz) {
                        float4 sv = ((const float4*)(Sb + ((size_t)d * CC + c) * NXx))[q];
                        vv.x += sv.x; vv.y += sv.y; vv.z += sv.z; vv.w += sv.w;
                    }
                }
            }
        }
        ((float4*)obase)[i] = vv;
    }

    // never-taken generic overflow fixup (entries with iz != owner's s_iz)
    int nov = *ovcnt;
    if (nov > 0) {
        __syncthreads();
        if (t == 0) {
            if (nov > OVCAP) nov = OVCAP;
            for (int k = 0; k < nov; ++k) {
                int ent = ovlist[k];
                int eb  = (ent >> 29) & 7;
                int ed  = (ent >> 23) & 63;
                int ew  = (ent >> 16) & 127;
                int eix = (ent >> 8) & 255;
                int eiz = ent & 255;
                if (eb == b && eiz >= iz0 && eiz < iz0 + 50) {
                    size_t o = (((size_t)b * CC + c) * NZz + eiz) * NXx + eix;
                    out[o] += P[(((size_t)eb * DD + ed) * FWw + ew) * CC + c];
                }
            }
        }
    }
}

extern "C" void kernel_launch(void* const* d_in, const int* in_sizes, int n_in,
                              void* d_out, int out_size, void* d_ws, size_t ws_size,
                              hipStream_t stream)
{
    const float* x          = (const float*)d_in[0];
    const float* intrins    = (const float*)d_in[1];
    const float* post_rots  = (const float*)d_in[2];
    const float* post_trans = (const float*)d_in[3];
    float* out = (float*)d_out;

    int B = in_sizes[0] / (NCH * (int)PLANE);

    size_t off = 0;
    auto alloc = [&](size_t bytes) {
        void* p = (char*)d_ws + off;
        off = (off + bytes + 255) & ~(size_t)255;
        return p;
    };
    float* P      = (float*)alloc((size_t)B * NE * CC * sizeof(float));       // 3.7 MB
    int*   V      = (int*)  alloc((size_t)B * NE * sizeof(int));
    float* S      = (float*)alloc((size_t)B * DD * CC * NXx * sizeof(float)); // 8.4 MB
    int*   izd    = (int*)  alloc((size_t)B * DD * sizeof(int));
    int*   rowcnt = (int*)  alloc((size_t)B * NZz * sizeof(int));
    int*   dlist  = (int*)  alloc((size_t)B * NZz * DCAP * sizeof(int));
    int*   ovcnt  = (int*)  alloc(256);
    int*   ovlist = (int*)  alloc((size_t)OVCAP * sizeof(int));

    lss_colpool<<<B * FWw * 2, 256, 0, stream>>>(x, intrins, post_rots, post_trans,
                                                 P, V, rowcnt, ovcnt);
    lss_rowbuild<<<B * DD * 8, 256, 0, stream>>>(P, V, S, izd, rowcnt, dlist,
                                                 ovcnt, ovlist);
    lss_writeout<<<B * CC * 4, 256, 0, stream>>>(S, izd, rowcnt, dlist, P,
                                                 ovcnt, ovlist, out);
}

// Round 10
// 100.919 us; speedup vs baseline: 1.3541x; 1.0347x over previous
//
#include <hip/hip_runtime.h>
#include <math.h>

#define DD   41     // depth bins
#define FHh  32
#define FWw  88
#define CC   64     // camera channels
#define CH   32     // channels per colpool half
#define CG8  8      // channels per rowbuild block
#define NXx  200
#define NZz  200
#define NCH  (DD + CC)              // 105
#define PLANE ((size_t)FHh * FWw)   // 2816
#define NE   (DD * FWw)             // 3608
#define DCAP 4
#define OVCAP 4096
// x: (B, 105, 32, 88) fp32 ; out: (B, 64, 200, 200) fp32

// ---------- Kernel A: per-(b,w,c-half) column pool ----------
__global__ __launch_bounds__(256) void lss_colpool(
    const float* __restrict__ x,
    const float* __restrict__ intrins,
    const float* __restrict__ post_rots,
    const float* __restrict__ post_trans,
    float* __restrict__ P, int* __restrict__ V,
    int* __restrict__ rowcnt8, int* __restrict__ ovcnt)
{
    __shared__ float Wt[DD][FHh + 1];   // logits -> masked softmax weights
    __shared__ float F4s[FHh][36];      // half-F [h][c], row 36 floats (16B-aligned)
    __shared__ float Mi[18];            // inv(post_rots), inv(intrins)
    __shared__ float pm[8][FHh + 1];    // partial max / sum
    __shared__ int   Vtmp[DD];

    int blk   = blockIdx.x;
    int chalf = blk & 1;
    int w     = (blk >> 1) % FWw;
    int b     = blk / (2 * FWw);
    int t     = threadIdx.x;
    const float* xb = x + (size_t)b * NCH * PLANE + w;

    for (int idx = t; idx < DD * FHh; idx += 256) {
        int d = idx >> 5, h = idx & 31;
        Wt[d][h] = xb[((size_t)d * FHh + h) * FWw];
    }
    for (int idx = t; idx < FHh * CH; idx += 256) {
        int c = idx & 31, h = idx >> 5;
        F4s[h][c] = xb[((size_t)(DD + chalf * CH + c) * FHh + h) * FWw];
    }
    if (t >= 64 && t < 64 + DD) Vtmp[t - 64] = -1;
    if (t == 0) {
        #pragma clang fp contract(off)
        // adjugate inverse; exact for identity rots / triangular K -> entries
        // are single correctly-rounded divisions, matching jnp.linalg.inv.
        for (int m = 0; m < 2; ++m) {
            const float* A = (m == 0 ? post_rots : intrins) + b * 9;
            float* O = Mi + m * 9;
            float a = A[0], bb = A[1], c = A[2];
            float d = A[3], e  = A[4], f = A[5];
            float g = A[6], h  = A[7], i = A[8];
            float det = a * (e * i - f * h) - bb * (d * i - f * g) + c * (d * h - e * g);
            O[0] = (e * i - f * h) / det;
            O[1] = (c * h - bb * i) / det;
            O[2] = (bb * f - c * e) / det;
            O[3] = (f * g - d * i) / det;
            O[4] = (a * i - c * g) / det;
            O[5] = (c * d - a * f) / det;
            O[6] = (d * h - e * g) / det;
            O[7] = (bb * g - a * h) / det;
            O[8] = (a * e - bb * d) / det;
        }
    }
    __syncthreads();

    // ---- parallel softmax: thread (h = t&31, l = t>>5) owns d = l+8k ----
    int h = t & 31, l = t >> 5;
    float e_[6];
    {
        float pmax = -INFINITY;
        for (int d = l; d < DD; d += 8) pmax = fmaxf(pmax, Wt[d][h]);
        pm[l][h] = pmax;
    }
    __syncthreads();
    float mx = -INFINITY;
    for (int j = 0; j < 8; ++j) mx = fmaxf(mx, pm[j][h]);
    __syncthreads();
    {
        #pragma clang fp contract(off)
        float psum = 0.0f;
        int k = 0;
        for (int d = l; d < DD; d += 8, ++k) {
            float e = expf(Wt[d][h] - mx);
            e_[k] = e; psum += e;
        }
        pm[l][h] = psum;
    }
    __syncthreads();
    float s = 0.0f;
    for (int j = 0; j < 8; ++j) s += pm[j][h];

    // ---- geometry per (d,h), honest mask ----
    {
        #pragma clang fp contract(off)
        float xs = (float)((double)w * 703.0 / 87.0);   // linspace(0,703,88)
        float ys = (float)((double)h * 255.0 / 31.0);   // linspace(0,255,32)
        float tx = post_trans[b * 3 + 0];
        float ty = post_trans[b * 3 + 1];
        float tz = post_trans[b * 3 + 2];
        int k = 0;
        for (int d = l; d < DD; d += 8, ++k) {
            float z  = 4.0f + (float)d;
            float px = xs - tx, py = ys - ty, pz = z - tz;
            float rx = Mi[0] * px + Mi[1] * py + Mi[2] * pz;
            float ry = Mi[3] * px + Mi[4] * py + Mi[5] * pz;
            float rz = Mi[6] * px + Mi[7] * py + Mi[8] * pz;
            float qx = rx * rz, qy = ry * rz, qz = rz;
            float gx = Mi[ 9] * qx + Mi[10] * qy + Mi[11] * qz;
            float gy = Mi[12] * qx + Mi[13] * qy + Mi[14] * qz;
            float gz = Mi[15] * qx + Mi[16] * qy + Mi[17] * qz;
            float cx = (gx + 50.0f) / 0.5f;
            float cy = (gy + 10.0f) / 20.0f;
            float cz = gz / 0.25f;
            int ix = (int)cx;   // trunc == numpy astype(int32)
            int iy = (int)cy;
            int iz = (int)cz;
            bool kept = (ix >= 0) & (ix < NXx) & (iy == 0) & (iz >= 0) & (iz < NZz);
            if (kept) {
                Wt[d][h] = e_[k] / s;
                Vtmp[d] = iz * NXx + ix;   // benign same-value race in practice;
                                           // w-mismatches handled via overflow path
            } else {
                Wt[d][h] = 0.0f;
            }
        }
    }
    __syncthreads();

    // ---- pool: P[b][d][w][chalf*32 ..] = sum_h Wt[d][h]*F[h][c] ----
    float* Pb = P + ((size_t)b * NE) * CC + chalf * CH;
    {
        int c4 = t & 7;
        for (int d = t >> 3; d < DD; d += 32) {
            float4 acc = make_float4(0.f, 0.f, 0.f, 0.f);
            for (int hh = 0; hh < FHh; ++hh) {
                float wtv = Wt[d][hh];
                float4 fv = *(const float4*)&F4s[hh][c4 * 4];
                acc.x += wtv * fv.x; acc.y += wtv * fv.y;
                acc.z += wtv * fv.z; acc.w += wtv * fv.w;
            }
            *(float4*)&Pb[((size_t)d * FWw + w) * CC + c4 * 4] = acc;
        }
    }
    if (chalf == 0) {
        if (t < DD) V[(size_t)b * NE + (size_t)t * FWw + w] = Vtmp[t];
        if (w == 0) for (int i = t; i < NZz * 8; i += 256) rowcnt8[b * NZz * 8 + i] = 0;
    }
    if (blk == 0 && t == 0) *ovcnt = 0;
}

// ---------- Kernel B: per-(b,d,8ch) row build; owner0 writes out directly ----------
__global__ __launch_bounds__(256) void lss_rowbuild(
    const float* __restrict__ P, const int* __restrict__ V,
    float* __restrict__ S, int* __restrict__ izd,
    int* __restrict__ rowcnt8, int* __restrict__ dlist8,
    int* __restrict__ ovcnt, int* __restrict__ ovlist,
    float* __restrict__ out)
{
    __shared__ float acc[CG8 * (NXx + 1)];
    __shared__ int ixw[FWw];
    __shared__ int izw[FWw];
    __shared__ int key;
    __shared__ int s_k;

    int blk = blockIdx.x;
    int cg = blk & 7;
    int bd = blk >> 3;
    int d = bd % DD;
    int b = bd / DD;
    int t = threadIdx.x;

    if (t == 0) key = 0x7fffffff;
    for (int i = t; i < CG8 * (NXx + 1); i += 256) acc[i] = 0.0f;
    __syncthreads();
    if (t < FWw) {
        int v = V[(size_t)bd * FWw + t];
        if (v >= 0) {
            int iz = v / NXx;
            izw[t] = iz; ixw[t] = v - iz * NXx;
            atomicMin(&key, (t << 16) | iz);
        } else { izw[t] = -1; ixw[t] = -1; }
    }
    __syncthreads();
    int kk = key;
    int s_iz = (kk == 0x7fffffff) ? -1 : (kk & 0xffff);  // iz of min-w kept entry
    if (cg == 0 && t == 0) izd[bd] = s_iz;
    if (s_iz < 0) return;

    int r = b * NZz + s_iz;
    if (t == 0) {
        int k = atomicAdd(&rowcnt8[r * 8 + cg], 1);
        if (k < DCAP) dlist8[(r * 8 + cg) * DCAP + k] = d;
        s_k = k;
    }
    // generic path: kept entries whose iz != s_iz go to the overflow list
    if (cg == 0 && t < FWw && izw[t] >= 0 && izw[t] != s_iz) {
        int k = atomicAdd(ovcnt, 1);
        if (k < OVCAP)
            ovlist[k] = (b << 29) | (d << 23) | (t << 16) | (ixw[t] << 8) | izw[t];
    }

    const float* Pb = P + (size_t)bd * FWw * CC + cg * CG8;
    for (int idx = t; idx < FWw * 2; idx += 256) {
        int w = idx >> 1, q = idx & 1;
        if (izw[w] == s_iz) {
            float4 v = *(const float4*)&Pb[(size_t)w * CC + q * 4];
            int ix = ixw[w];
            int cb = q * 4;
            atomicAdd(&acc[(cb + 0) * (NXx + 1) + ix], v.x);
            atomicAdd(&acc[(cb + 1) * (NXx + 1) + ix], v.y);
            atomicAdd(&acc[(cb + 2) * (NXx + 1) + ix], v.z);
            atomicAdd(&acc[(cb + 3) * (NXx + 1) + ix], v.w);
        }
    }
    __syncthreads();

    // owner 0 (the common case) writes its dense row straight to out;
    // later owners (collisions, never in practice) park in S for the fixup.
    bool owner0 = (s_k == 0);
    for (int i = t; i < CG8 * (NXx / 4); i += 256) {
        int c = i / (NXx / 4), q = i - c * (NXx / 4);
        int base = c * (NXx + 1) + q * 4;
        float4 vv;
        vv.x = acc[base + 0];
        vv.y = acc[base + 1];
        vv.z = acc[base + 2];
        vv.w = acc[base + 3];
        if (owner0) {
            float* orow = out + (((size_t)(b * CC + cg * CG8 + c)) * NZz + s_iz) * NXx;
            ((float4*)orow)[q] = vv;
        } else {
            float* Srow = S + ((size_t)bd * CC + cg * CG8 + c) * NXx;
            ((float4*)Srow)[q] = vv;
        }
    }
}

// ---------- Kernel C: zero-fill + dormant collision/overflow fixup ----------
__global__ __launch_bounds__(256) void lss_writeout(
    const float* __restrict__ S, const int* __restrict__ izd,
    const int* __restrict__ rowcnt8, const int* __restrict__ dlist8,
    const float* __restrict__ P,
    const int* __restrict__ ovcnt, const int* __restrict__ ovlist,
    float* __restrict__ out)
{
    __shared__ int s_n[50];
    __shared__ int s_d[50 * DCAP];

    int blk = blockIdx.x;
    int qz = blk & 3;
    int bc = blk >> 2;
    int c  = bc % CC;
    int b  = bc / CC;
    int cg = c >> 3;
    int iz0 = qz * 50;
    int t = threadIdx.x;

    for (int i = t; i < 50; i += 256)
        s_n[i] = rowcnt8[(b * NZz + iz0 + i) * 8 + cg];
    for (int i = t; i < 50 * DCAP; i += 256) {
        int row = i / DCAP, k = i - row * DCAP;
        s_d[i] = dlist8[((b * NZz + iz0 + row) * 8 + cg) * DCAP + k];
    }
    __syncthreads();

    float* obase = out + (((size_t)b * CC + c) * NZz + iz0) * NXx;  // 40KB span
    const float* Sb = S + (size_t)b * DD * CC * NXx;

    for (int i = t; i < 50 * (NXx / 4); i += 256) {
        int izl = i / (NXx / 4), q = i - izl * (NXx / 4);
        int n = s_n[izl];
        if (n == 1) continue;                    // owner0 already wrote this row
        float4 vv = make_float4(0.f, 0.f, 0.f, 0.f);
        if (n > 1) {
            // dormant collision merge: out row (owner0) + S rows (owners 1..)
            float4 cur = ((float4*)obase)[i];
            vv.x += cur.x; vv.y += cur.y; vv.z += cur.z; vv.w += cur.w;
            if (n <= DCAP) {
                for (int k = 1; k < n; ++k) {
                    int d = s_d[izl * DCAP + k];
                    float4 sv = ((const float4*)(Sb + ((size_t)d * CC + c) * NXx))[q];
                    vv.x += sv.x; vv.y += sv.y; vv.z += sv.z; vv.w += sv.w;
                }
            } else {
                int iz = iz0 + izl;
                int owner0 = s_d[izl * DCAP + 0];
                for (int d = 0; d < DD; ++d) {
                    if (izd[b * DD + d] == iz && d != owner0) {
                        float4 sv = ((const float4*)(Sb + ((size_t)d * CC + c) * NXx))[q];
                        vv.x += sv.x; vv.y += sv.y; vv.z += sv.z; vv.w += sv.w;
                    }
                }
            }
        }
        ((float4*)obase)[i] = vv;
    }

    // dormant generic overflow fixup (entries with iz != owner's s_iz)
    int nov = *ovcnt;
    if (nov > 0) {
        __syncthreads();
        if (t == 0) {
            if (nov > OVCAP) nov = OVCAP;
            for (int k = 0; k < nov; ++k) {
                int ent = ovlist[k];
                int eb  = (ent >> 29) & 7;
                int ed  = (ent >> 23) & 63;
                int ew  = (ent >> 16) & 127;
                int eix = (ent >> 8) & 255;
                int eiz = ent & 255;
                if (eb == b && eiz >= iz0 && eiz < iz0 + 50) {
                    size_t o = (((size_t)b * CC + c) * NZz + eiz) * NXx + eix;
                    out[o] += P[(((size_t)eb * DD + ed) * FWw + ew) * CC + c];
                }
            }
        }
    }
}

extern "C" void kernel_launch(void* const* d_in, const int* in_sizes, int n_in,
                              void* d_out, int out_size, void* d_ws, size_t ws_size,
                              hipStream_t stream)
{
    const float* x          = (const float*)d_in[0];
    const float* intrins    = (const float*)d_in[1];
    const float* post_rots  = (const float*)d_in[2];
    const float* post_trans = (const float*)d_in[3];
    float* out = (float*)d_out;

    int B = in_sizes[0] / (NCH * (int)PLANE);

    size_t off = 0;
    auto alloc = [&](size_t bytes) {
        void* p = (char*)d_ws + off;
        off = (off + bytes + 255) & ~(size_t)255;
        return p;
    };
    float* P       = (float*)alloc((size_t)B * NE * CC * sizeof(float));       // 3.7 MB
    int*   V       = (int*)  alloc((size_t)B * NE * sizeof(int));
    float* S       = (float*)alloc((size_t)B * DD * CC * NXx * sizeof(float)); // 8.4 MB (dormant)
    int*   izd     = (int*)  alloc((size_t)B * DD * sizeof(int));
    int*   rowcnt8 = (int*)  alloc((size_t)B * NZz * 8 * sizeof(int));
    int*   dlist8  = (int*)  alloc((size_t)B * NZz * 8 * DCAP * sizeof(int));
    int*   ovcnt   = (int*)  alloc(256);
    int*   ovlist  = (int*)  alloc((size_t)OVCAP * sizeof(int));

    lss_colpool<<<B * FWw * 2, 256, 0, stream>>>(x, intrins, post_rots, post_trans,
                                                 P, V, rowcnt8, ovcnt);
    lss_rowbuild<<<B * DD * 8, 256, 0, stream>>>(P, V, S, izd, rowcnt8, dlist8,
                                                 ovcnt, ovlist, out);
    lss_writeout<<<B * CC * 4, 256, 0, stream>>>(S, izd, rowcnt8, dlist8, P,
                                                 ovcnt, ovlist, out);
}

// Round 11
// 99.604 us; speedup vs baseline: 1.3719x; 1.0132x over previous
//
#include <hip/hip_runtime.h>
#include <math.h>

#define DD   41     // depth bins
#define FHh  32
#define FWw  88
#define CC   64     // camera channels
#define CH   32     // channels per colpool half
#define CG8  8      // channels per rowbuild block
#define NXx  200
#define NZz  200
#define NCH  (DD + CC)              // 105
#define PLANE ((size_t)FHh * FWw)   // 2816
#define NE   (DD * FWw)             // 3608
#define DCAP 4
#define OVCAP 4096
// x: (B, 105, 32, 88) fp32 ; out: (B, 64, 200, 200) fp32

// ---------- Kernel A: per-(b,w,c-half) column pool + output zero-fill ----------
__global__ __launch_bounds__(256) void lss_colpool(
    const float* __restrict__ x,
    const float* __restrict__ intrins,
    const float* __restrict__ post_rots,
    const float* __restrict__ post_trans,
    float* __restrict__ P, int* __restrict__ V,
    int* __restrict__ rowcnt8, int* __restrict__ ovcnt,
    float* __restrict__ out, int out_quads)
{
    __shared__ float Wt[DD][FHh + 1];   // logits -> masked softmax weights
    __shared__ float F4s[FHh][36];      // half-F [h][c], row 36 floats (16B-aligned)
    __shared__ float Mi[18];            // inv(post_rots), inv(intrins)
    __shared__ float pm[8][FHh + 1];    // partial max / sum
    __shared__ int   Vtmp[DD];

    int blk   = blockIdx.x;
    int chalf = blk & 1;
    int w     = (blk >> 1) % FWw;
    int b     = blk / (2 * FWw);
    int t     = threadIdx.x;
    const float* xb = x + (size_t)b * NCH * PLANE + w;

    for (int idx = t; idx < DD * FHh; idx += 256) {
        int d = idx >> 5, h = idx & 31;
        Wt[d][h] = xb[((size_t)d * FHh + h) * FWw];
    }
    for (int idx = t; idx < FHh * CH; idx += 256) {
        int c = idx & 31, h = idx >> 5;
        F4s[h][c] = xb[((size_t)(DD + chalf * CH + c) * FHh + h) * FWw];
    }
    if (t >= 64 && t < 64 + DD) Vtmp[t - 64] = -1;
    if (t == 0) {
        #pragma clang fp contract(off)
        // adjugate inverse; exact for identity rots / triangular K -> entries
        // are single correctly-rounded divisions, matching jnp.linalg.inv.
        for (int m = 0; m < 2; ++m) {
            const float* A = (m == 0 ? post_rots : intrins) + b * 9;
            float* O = Mi + m * 9;
            float a = A[0], bb = A[1], c = A[2];
            float d = A[3], e  = A[4], f = A[5];
            float g = A[6], h  = A[7], i = A[8];
            float det = a * (e * i - f * h) - bb * (d * i - f * g) + c * (d * h - e * g);
            O[0] = (e * i - f * h) / det;
            O[1] = (c * h - bb * i) / det;
            O[2] = (bb * f - c * e) / det;
            O[3] = (f * g - d * i) / det;
            O[4] = (a * i - c * g) / det;
            O[5] = (c * d - a * f) / det;
            O[6] = (d * h - e * g) / det;
            O[7] = (bb * g - a * h) / det;
            O[8] = (a * e - bb * d) / det;
        }
    }
    __syncthreads();

    // ---- parallel softmax: thread (h = t&31, l = t>>5) owns d = l+8k ----
    int h = t & 31, l = t >> 5;
    float e_[6];
    {
        float pmax = -INFINITY;
        for (int d = l; d < DD; d += 8) pmax = fmaxf(pmax, Wt[d][h]);
        pm[l][h] = pmax;
    }
    __syncthreads();
    float mx = -INFINITY;
    for (int j = 0; j < 8; ++j) mx = fmaxf(mx, pm[j][h]);
    __syncthreads();
    {
        #pragma clang fp contract(off)
        float psum = 0.0f;
        int k = 0;
        for (int d = l; d < DD; d += 8, ++k) {
            float e = expf(Wt[d][h] - mx);
            e_[k] = e; psum += e;
        }
        pm[l][h] = psum;
    }
    __syncthreads();
    float s = 0.0f;
    for (int j = 0; j < 8; ++j) s += pm[j][h];

    // ---- geometry per (d,h), honest mask ----
    {
        #pragma clang fp contract(off)
        float xs = (float)((double)w * 703.0 / 87.0);   // linspace(0,703,88)
        float ys = (float)((double)h * 255.0 / 31.0);   // linspace(0,255,32)
        float tx = post_trans[b * 3 + 0];
        float ty = post_trans[b * 3 + 1];
        float tz = post_trans[b * 3 + 2];
        int k = 0;
        for (int d = l; d < DD; d += 8, ++k) {
            float z  = 4.0f + (float)d;
            float px = xs - tx, py = ys - ty, pz = z - tz;
            float rx = Mi[0] * px + Mi[1] * py + Mi[2] * pz;
            float ry = Mi[3] * px + Mi[4] * py + Mi[5] * pz;
            float rz = Mi[6] * px + Mi[7] * py + Mi[8] * pz;
            float qx = rx * rz, qy = ry * rz, qz = rz;
            float gx = Mi[ 9] * qx + Mi[10] * qy + Mi[11] * qz;
            float gy = Mi[12] * qx + Mi[13] * qy + Mi[14] * qz;
            float gz = Mi[15] * qx + Mi[16] * qy + Mi[17] * qz;
            float cx = (gx + 50.0f) / 0.5f;
            float cy = (gy + 10.0f) / 20.0f;
            float cz = gz / 0.25f;
            int ix = (int)cx;   // trunc == numpy astype(int32)
            int iy = (int)cy;
            int iz = (int)cz;
            bool kept = (ix >= 0) & (ix < NXx) & (iy == 0) & (iz >= 0) & (iz < NZz);
            if (kept) {
                Wt[d][h] = e_[k] / s;
                Vtmp[d] = iz * NXx + ix;   // benign same-value race in practice;
                                           // w-mismatches handled via overflow path
            } else {
                Wt[d][h] = 0.0f;
            }
        }
    }
    __syncthreads();

    // ---- pool: P[b][d][w][chalf*32 ..] = sum_h Wt[d][h]*F[h][c] ----
    float* Pb = P + ((size_t)b * NE) * CC + chalf * CH;
    {
        int c4 = t & 7;
        for (int d = t >> 3; d < DD; d += 32) {
            float4 acc = make_float4(0.f, 0.f, 0.f, 0.f);
            for (int hh = 0; hh < FHh; ++hh) {
                float wtv = Wt[d][hh];
                float4 fv = *(const float4*)&F4s[hh][c4 * 4];
                acc.x += wtv * fv.x; acc.y += wtv * fv.y;
                acc.z += wtv * fv.z; acc.w += wtv * fv.w;
            }
            *(float4*)&Pb[((size_t)d * FWw + w) * CC + c4 * 4] = acc;
        }
    }
    if (chalf == 0) {
        if (t < DD) V[(size_t)b * NE + (size_t)t * FWw + w] = Vtmp[t];
        if (w == 0) for (int i = t; i < NZz * 8; i += 256) rowcnt8[b * NZz * 8 + i] = 0;
    }
    if (blk == 0 && t == 0) *ovcnt = 0;

    // ---- tail: stream the whole output to zero (grid-stride float4) ----
    {
        float4 z = make_float4(0.f, 0.f, 0.f, 0.f);
        float4* o4 = (float4*)out;
        int stride = gridDim.x * 256;
        for (int i = blk * 256 + t; i < out_quads; i += stride) o4[i] = z;
    }
}

// ---------- Kernel B: per-(b,d,8ch) row build; owner0 writes out directly ----------
__global__ __launch_bounds__(256) void lss_rowbuild(
    const float* __restrict__ P, const int* __restrict__ V,
    float* __restrict__ S, int* __restrict__ izd,
    int* __restrict__ rowcnt8, int* __restrict__ dlist8,
    int* __restrict__ ovcnt, int* __restrict__ ovlist,
    float* __restrict__ out)
{
    __shared__ float acc[CG8 * (NXx + 1)];
    __shared__ int ixw[FWw];
    __shared__ int izw[FWw];
    __shared__ int key;
    __shared__ int s_k;

    int blk = blockIdx.x;
    int cg = blk & 7;
    int bd = blk >> 3;
    int d = bd % DD;
    int b = bd / DD;
    int t = threadIdx.x;

    if (t == 0) key = 0x7fffffff;
    for (int i = t; i < CG8 * (NXx + 1); i += 256) acc[i] = 0.0f;
    __syncthreads();
    if (t < FWw) {
        int v = V[(size_t)bd * FWw + t];
        if (v >= 0) {
            int iz = v / NXx;
            izw[t] = iz; ixw[t] = v - iz * NXx;
            atomicMin(&key, (t << 16) | iz);
        } else { izw[t] = -1; ixw[t] = -1; }
    }
    __syncthreads();
    int kk = key;
    int s_iz = (kk == 0x7fffffff) ? -1 : (kk & 0xffff);  // iz of min-w kept entry
    if (cg == 0 && t == 0) izd[bd] = s_iz;
    if (s_iz < 0) return;

    int r = b * NZz + s_iz;
    if (t == 0) {
        int k = atomicAdd(&rowcnt8[r * 8 + cg], 1);
        if (k < DCAP) dlist8[(r * 8 + cg) * DCAP + k] = d;
        s_k = k;
    }
    // generic path: kept entries whose iz != s_iz go to the overflow list
    if (cg == 0 && t < FWw && izw[t] >= 0 && izw[t] != s_iz) {
        int k = atomicAdd(ovcnt, 1);
        if (k < OVCAP)
            ovlist[k] = (b << 29) | (d << 23) | (t << 16) | (ixw[t] << 8) | izw[t];
    }

    const float* Pb = P + (size_t)bd * FWw * CC + cg * CG8;
    for (int idx = t; idx < FWw * 2; idx += 256) {
        int w = idx >> 1, q = idx & 1;
        if (izw[w] == s_iz) {
            float4 v = *(const float4*)&Pb[(size_t)w * CC + q * 4];
            int ix = ixw[w];
            int cb = q * 4;
            atomicAdd(&acc[(cb + 0) * (NXx + 1) + ix], v.x);
            atomicAdd(&acc[(cb + 1) * (NXx + 1) + ix], v.y);
            atomicAdd(&acc[(cb + 2) * (NXx + 1) + ix], v.z);
            atomicAdd(&acc[(cb + 3) * (NXx + 1) + ix], v.w);
        }
    }
    __syncthreads();

    // owner 0 (the common case) overwrites its zero-filled row in out;
    // later owners (collisions, never in practice) park in S for the fixup.
    bool owner0 = (s_k == 0);
    for (int i = t; i < CG8 * (NXx / 4); i += 256) {
        int c = i / (NXx / 4), q = i - c * (NXx / 4);
        int base = c * (NXx + 1) + q * 4;
        float4 vv;
        vv.x = acc[base + 0];
        vv.y = acc[base + 1];
        vv.z = acc[base + 2];
        vv.w = acc[base + 3];
        if (owner0) {
            float* orow = out + (((size_t)(b * CC + cg * CG8 + c)) * NZz + s_iz) * NXx;
            ((float4*)orow)[q] = vv;
        } else {
            float* Srow = S + ((size_t)bd * CC + cg * CG8 + c) * NXx;
            ((float4*)Srow)[q] = vv;
        }
    }
}

// ---------- Kernel C: dormant collision/overflow fixup (early-exits) ----------
__global__ __launch_bounds__(256) void lss_fixup(
    const float* __restrict__ S, const int* __restrict__ izd,
    const int* __restrict__ rowcnt8, const int* __restrict__ dlist8,
    const float* __restrict__ P,
    const int* __restrict__ ovcnt, const int* __restrict__ ovlist,
    float* __restrict__ out)
{
    int b = blockIdx.x;
    int t = threadIdx.x;

    // collision merge: one thread per (iz, cg) pair with n > 1 (never in practice)
    for (int pair = t; pair < NZz * 8; pair += 256) {
        int n = rowcnt8[b * NZz * 8 + pair];
        if (n <= 1) continue;
        int iz = pair >> 3, cg = pair & 7;
        const int* dl = dlist8 + (size_t)(b * NZz * 8 + pair) * DCAP;
        if (n <= DCAP) {
            for (int k = 1; k < n; ++k) {
                int d = dl[k];
                for (int c = 0; c < CG8; ++c) {
                    const float* Srow = S + ((size_t)(b * DD + d) * CC + cg * CG8 + c) * NXx;
                    float* orow = out + (((size_t)(b * CC + cg * CG8 + c)) * NZz + iz) * NXx;
                    for (int ix = 0; ix < NXx; ++ix) atomicAdd(&orow[ix], Srow[ix]);
                }
            }
        } else {
            int owner0 = dl[0];
            for (int d = 0; d < DD; ++d) {
                if (izd[b * DD + d] == iz && d != owner0) {
                    for (int c = 0; c < CG8; ++c) {
                        const float* Srow = S + ((size_t)(b * DD + d) * CC + cg * CG8 + c) * NXx;
                        float* orow = out + (((size_t)(b * CC + cg * CG8 + c)) * NZz + iz) * NXx;
                        for (int ix = 0; ix < NXx; ++ix) atomicAdd(&orow[ix], Srow[ix]);
                    }
                }
            }
        }
    }

    // dormant generic overflow fixup (entries with iz != owner's s_iz)
    if (b == 0 && t == 0) {
        int nov = *ovcnt;
        if (nov > OVCAP) nov = OVCAP;
        for (int k = 0; k < nov; ++k) {
            int ent = ovlist[k];
            int eb  = (ent >> 29) & 7;
            int ed  = (ent >> 23) & 63;
            int ew  = (ent >> 16) & 127;
            int eix = (ent >> 8) & 255;
            int eiz = ent & 255;
            for (int c = 0; c < CC; ++c) {
                size_t o = (((size_t)(eb * CC + c)) * NZz + eiz) * NXx + eix;
                atomicAdd(&out[o], P[(((size_t)eb * DD + ed) * FWw + ew) * CC + c]);
            }
        }
    }
}

extern "C" void kernel_launch(void* const* d_in, const int* in_sizes, int n_in,
                              void* d_out, int out_size, void* d_ws, size_t ws_size,
                              hipStream_t stream)
{
    const float* x          = (const float*)d_in[0];
    const float* intrins    = (const float*)d_in[1];
    const float* post_rots  = (const float*)d_in[2];
    const float* post_trans = (const float*)d_in[3];
    float* out = (float*)d_out;

    int B = in_sizes[0] / (NCH * (int)PLANE);

    size_t off = 0;
    auto alloc = [&](size_t bytes) {
        void* p = (char*)d_ws + off;
        off = (off + bytes + 255) & ~(size_t)255;
        return p;
    };
    float* P       = (float*)alloc((size_t)B * NE * CC * sizeof(float));       // 3.7 MB
    int*   V       = (int*)  alloc((size_t)B * NE * sizeof(int));
    float* S       = (float*)alloc((size_t)B * DD * CC * NXx * sizeof(float)); // 8.4 MB (dormant)
    int*   izd     = (int*)  alloc((size_t)B * DD * sizeof(int));
    int*   rowcnt8 = (int*)  alloc((size_t)B * NZz * 8 * sizeof(int));
    int*   dlist8  = (int*)  alloc((size_t)B * NZz * 8 * DCAP * sizeof(int));
    int*   ovcnt   = (int*)  alloc(256);
    int*   ovlist  = (int*)  alloc((size_t)OVCAP * sizeof(int));

    int out_quads = out_size / 4;

    lss_colpool<<<B * FWw * 2, 256, 0, stream>>>(x, intrins, post_rots, post_trans,
                                                 P, V, rowcnt8, ovcnt, out, out_quads);
    lss_rowbuild<<<B * DD * 8, 256, 0, stream>>>(P, V, S, izd, rowcnt8, dlist8,
                                                 ovcnt, ovlist, out);
    lss_fixup<<<B, 256, 0, stream>>>(S, izd, rowcnt8, dlist8, P, ovcnt, ovlist, out);
}